// Round 1
// baseline (254.961 us; speedup 1.0000x reference)
//
#include <hip/hip_runtime.h>
#include <hip/hip_bf16.h>

#define B_SZ   2
#define N_SEQ  2048
#define NH     16
#define DH     128
#define DM     2048
#define QBLK   64
#define KVBLK  32
#define NQT    (N_SEQ / QBLK)
#define MASK_VAL (-50000.0f)

typedef short bf16x8 __attribute__((ext_vector_type(8)));
typedef short bf16x4 __attribute__((ext_vector_type(4)));
typedef float f32x4  __attribute__((ext_vector_type(4)));

__device__ __forceinline__ short f2bf(float x) {
  unsigned u = __builtin_bit_cast(unsigned, x);
  unsigned r = (u + 0x7fffu + ((u >> 16) & 1u)) >> 16;
  return (short)r;
}

// swizzle for VT rows (row length 64B): spread 16B blocks
__device__ __forceinline__ int vswz(int d) {
  return (((d & 3) ^ ((d >> 2) & 3)) << 4);
}
// swizzle for P rows (row length 64B)
__device__ __forceinline__ int pswz(int row) {
  return (((row & 3) ^ ((row >> 2) & 3)) << 4);
}

__global__ __launch_bounds__(256, 4)
void attn_fwd(const float* __restrict__ q, const float* __restrict__ k,
              const float* __restrict__ v, float* __restrict__ out) {
  __shared__ __align__(16) char lds[20480];
  char* ldsK  = lds;            // [32 rows][256 B] bf16 K-tile, XOR-swizzled
  char* ldsVT = lds + 8192;     // [128 rows][64 B] bf16 V^T-tile, swizzled
  char* ldsP  = lds + 16384;    // per-wave [16][64 B] P staging

  const int tid  = threadIdx.x;
  const int lane = tid & 63;
  const int w    = tid >> 6;
  const int g    = lane >> 4;   // 16-lane group 0..3
  const int lr   = lane & 15;

  const int bid = blockIdx.x;
  const int bh  = bid % (B_SZ * NH);
  const int qt  = bid / (B_SZ * NH);
  const int b   = bh >> 4;
  const int h   = bh & 15;
  const int q0  = qt * QBLK;
  const int wq0 = q0 + w * 16;   // this wave's first q row

  const float scale = 0.08838834764831845f;  // 128^-0.5

  // ---- load Q fragments (A-layout: row = lr, k = g*8+j within 32-wide k-step)
  bf16x8 qf[4];
  {
    const float* qbase = q + ((size_t)b * N_SEQ + (wq0 + lr)) * DM + h * DH + g * 8;
    #pragma unroll
    for (int s = 0; s < 4; ++s) {
      float4 a = *(const float4*)(qbase + s * 32);
      float4 c = *(const float4*)(qbase + s * 32 + 4);
      qf[s][0] = f2bf(a.x * scale); qf[s][1] = f2bf(a.y * scale);
      qf[s][2] = f2bf(a.z * scale); qf[s][3] = f2bf(a.w * scale);
      qf[s][4] = f2bf(c.x * scale); qf[s][5] = f2bf(c.y * scale);
      qf[s][6] = f2bf(c.z * scale); qf[s][7] = f2bf(c.w * scale);
    }
  }

  float m_[4], ll_[4];
  f32x4 o[8];
  #pragma unroll
  for (int r = 0; r < 4; ++r) { m_[r] = -INFINITY; ll_[r] = 0.f; }
  #pragma unroll
  for (int dt = 0; dt < 8; ++dt) o[dt] = (f32x4){0.f, 0.f, 0.f, 0.f};

  const float* kb = k + (size_t)b * N_SEQ * DM + h * DH;
  const float* vb = v + (size_t)b * N_SEQ * DM + h * DH;

  const int jt_end = q0 + QBLK;
  for (int jt = 0; jt < jt_end; jt += KVBLK) {
    __syncthreads();   // previous tile's compute done before overwrite

    // ---- stage K tile [jt, jt+32) x 128 fp32 -> bf16 LDS, row-swizzled
    {
      const float* kt = kb + (size_t)jt * DM;
      #pragma unroll
      for (int i = 0; i < 4; ++i) {
        int idx = i * 256 + tid;     // 0..1023 float4s
        int row = idx >> 5;          // 0..31
        int c4  = idx & 31;          // float4 index in row
        float4 f = *(const float4*)(kt + (size_t)row * DM + c4 * 4);
        bf16x4 hv;
        hv[0] = f2bf(f.x); hv[1] = f2bf(f.y); hv[2] = f2bf(f.z); hv[3] = f2bf(f.w);
        *(bf16x4*)(ldsK + row * 256 + ((c4 * 8) ^ ((row & 7) << 4))) = hv;
      }
    }
    // ---- stage V^T: VT[d][j] bf16 (column-coalesced global reads)
    {
      const float* vt = vb + (size_t)jt * DM;
      int d   = tid & 127;
      int jb0 = tid >> 7;            // 0..1
      #pragma unroll
      for (int t2 = 0; t2 < 2; ++t2) {
        int jb = jb0 + t2 * 2;       // 8-col block of j
        bf16x8 hv;
        #pragma unroll
        for (int jj = 0; jj < 8; ++jj)
          hv[jj] = f2bf(vt[(size_t)(jb * 8 + jj) * DM + d]);
        *(bf16x8*)(ldsVT + d * 64 + ((jb * 16) ^ vswz(d))) = hv;
      }
    }
    __syncthreads();

    if (jt > wq0 + 15) continue;   // whole tile masked for this wave's rows

    // ---- S = (Q*scale) K^T : two 16x16 col-tiles, K-dim 128 in 4 steps
    f32x4 s0 = {0,0,0,0}, s1 = {0,0,0,0};
    #pragma unroll
    for (int s = 0; s < 4; ++s) {
      bf16x8 k0 = *(const bf16x8*)(ldsK + lr * 256 +
                    ((s * 64 + g * 16) ^ ((lr & 7) << 4)));
      bf16x8 k1 = *(const bf16x8*)(ldsK + (16 + lr) * 256 +
                    ((s * 64 + g * 16) ^ ((lr & 7) << 4)));
      s0 = __builtin_amdgcn_mfma_f32_16x16x32_bf16(qf[s], k0, s0, 0, 0, 0);
      s1 = __builtin_amdgcn_mfma_f32_16x16x32_bf16(qf[s], k1, s1, 0, 0, 0);
    }

    // ---- causal mask (D-layout: row = g*4+r, col = lr)
    if (jt + KVBLK > wq0 + 1) {
      #pragma unroll
      for (int r = 0; r < 4; ++r) {
        int irow = wq0 + g * 4 + r;
        s0[r] = (jt + lr      > irow) ? MASK_VAL : s0[r];
        s1[r] = (jt + 16 + lr > irow) ? MASK_VAL : s1[r];
      }
    }

    // ---- online softmax (row-reduce across the 16 lanes of the group)
    float tm[4];
    #pragma unroll
    for (int r = 0; r < 4; ++r) tm[r] = fmaxf(s0[r], s1[r]);
    #pragma unroll
    for (int off = 1; off < 16; off <<= 1) {
      #pragma unroll
      for (int r = 0; r < 4; ++r) tm[r] = fmaxf(tm[r], __shfl_xor(tm[r], off));
    }
    float alpha[4];
    #pragma unroll
    for (int r = 0; r < 4; ++r) {
      float mn = fmaxf(m_[r], tm[r]);
      alpha[r] = __expf(m_[r] - mn);
      m_[r] = mn;
      s0[r] = __expf(s0[r] - mn);
      s1[r] = __expf(s1[r] - mn);
    }
    float ts[4];
    #pragma unroll
    for (int r = 0; r < 4; ++r) ts[r] = s0[r] + s1[r];
    #pragma unroll
    for (int off = 1; off < 16; off <<= 1) {
      #pragma unroll
      for (int r = 0; r < 4; ++r) ts[r] += __shfl_xor(ts[r], off);
    }
    #pragma unroll
    for (int r = 0; r < 4; ++r) ll_[r] = ll_[r] * alpha[r] + ts[r];
    #pragma unroll
    for (int dt = 0; dt < 8; ++dt) {
      #pragma unroll
      for (int r = 0; r < 4; ++r) o[dt][r] *= alpha[r];
    }

    // ---- P (f32, D-layout) -> bf16 LDS -> A-fragment
    char* myP = ldsP + (w << 10);
    #pragma unroll
    for (int r = 0; r < 4; ++r) {
      int prow = g * 4 + r;
      int sw   = pswz(prow);
      *(short*)(myP + prow * 64 + ((lr * 2)        ^ sw)) = f2bf(s0[r]);
      *(short*)(myP + prow * 64 + (((16 + lr) * 2) ^ sw)) = f2bf(s1[r]);
    }
    bf16x8 pa = *(const bf16x8*)(myP + lr * 64 + ((g * 16) ^ pswz(lr)));

    // ---- O += P V  (B-frag from VT: contiguous 16B reads)
    #pragma unroll
    for (int dt = 0; dt < 8; ++dt) {
      int drow = dt * 16 + lr;
      bf16x8 vv = *(const bf16x8*)(ldsVT + drow * 64 + ((g * 16) ^ vswz(drow)));
      o[dt] = __builtin_amdgcn_mfma_f32_16x16x32_bf16(pa, vv, o[dt], 0, 0, 0);
    }
  }

  // ---- epilogue: normalize and store
  float inv[4];
  #pragma unroll
  for (int r = 0; r < 4; ++r) inv[r] = 1.0f / ll_[r];
  float* ob = out + ((size_t)b * N_SEQ + wq0) * DM + h * DH;
  #pragma unroll
  for (int dt = 0; dt < 8; ++dt) {
    #pragma unroll
    for (int r = 0; r < 4; ++r)
      ob[(size_t)(g * 4 + r) * DM + dt * 16 + lr] = o[dt][r] * inv[r];
  }
}

extern "C" void kernel_launch(void* const* d_in, const int* in_sizes, int n_in,
                              void* d_out, int out_size, void* d_ws, size_t ws_size,
                              hipStream_t stream) {
  const float* q = (const float*)d_in[0];
  const float* k = (const float*)d_in[1];
  const float* v = (const float*)d_in[2];
  float* out = (float*)d_out;
  dim3 grid(B_SZ * NH * NQT);   // 1024 blocks: (b,h) fastest for CU balance
  attn_fwd<<<grid, 256, 0, stream>>>(q, k, v, out);
}